// Round 1
// baseline (567.417 us; speedup 1.0000x reference)
//
#include <hip/hip_runtime.h>
#include <math.h>

#define NSEG 8
#define NPTS 32768
#define CH   256
#define CG   8
#define EPS_GN 1e-5f

// workspace layout (floats): accS[NSEG*CH] | accS2[NSEG*CH] | coeff[256*32]
// coeff per group (stride 32): [0]=K, [4..11]=P, [12..19]=Q, [20..27]=R

// ---------------- kernel 0: zero accumulators ----------------
__global__ __launch_bounds__(256) void k_zero(float* __restrict__ acc) {
  acc[blockIdx.x * 256 + threadIdx.x] = 0.0f;  // grid sized exactly (16*256 = 4096)
}

// ---------------- kernel 1: per (segment, channel) Σx, Σx² ----------------
__global__ __launch_bounds__(256) void k_reduce(const float* __restrict__ feat,
                                                float* __restrict__ accS,
                                                float* __restrict__ accS2) {
  const int blk   = blockIdx.x;      // 1024 = NSEG * 128
  const int seg   = blk >> 7;
  const int chunk = blk & 127;       // 128 chunks of 256 rows
  const int q  = threadIdx.x & 63;   // float4 column index (cols 4q..4q+3)
  const int dr = threadIdx.x >> 6;   // 0..3
  const float4* f4 = (const float4*)feat;
  const size_t rowbase = (size_t)seg * NPTS + (size_t)chunk * 256;
  float4 s  = make_float4(0.f, 0.f, 0.f, 0.f);
  float4 s2 = make_float4(0.f, 0.f, 0.f, 0.f);
  for (int r = dr; r < 256; r += 4) {
    float4 v = f4[(rowbase + r) * (CH / 4) + q];
    s.x += v.x;     s.y += v.y;     s.z += v.z;     s.w += v.w;
    s2.x += v.x*v.x; s2.y += v.y*v.y; s2.z += v.z*v.z; s2.w += v.w*v.w;
  }
  __shared__ float4 rs[256];
  __shared__ float4 rq[256];
  rs[threadIdx.x] = s;
  rq[threadIdx.x] = s2;
  __syncthreads();
  if (threadIdx.x < 64) {
    float4 a = rs[q], b = rs[64 + q], c = rs[128 + q], d = rs[192 + q];
    float4 e = rq[q], f = rq[64 + q], g = rq[128 + q], h = rq[192 + q];
    float sx = a.x + b.x + c.x + d.x;
    float sy = a.y + b.y + c.y + d.y;
    float sz = a.z + b.z + c.z + d.z;
    float sw = a.w + b.w + c.w + d.w;
    float tx = e.x + f.x + g.x + h.x;
    float ty = e.y + f.y + g.y + h.y;
    float tz = e.z + f.z + g.z + h.z;
    float tw = e.w + f.w + g.w + h.w;
    float* pS  = accS  + seg * CH + q * 4;
    float* pS2 = accS2 + seg * CH + q * 4;
    atomicAdd(pS + 0, sx);  atomicAdd(pS + 1, sy);
    atomicAdd(pS + 2, sz);  atomicAdd(pS + 3, sw);
    atomicAdd(pS2 + 0, tx); atomicAdd(pS2 + 1, ty);
    atomicAdd(pS2 + 2, tz); atomicAdd(pS2 + 3, tw);
  }
}

// ---------------- kernel 2: per-group coefficients ----------------
__global__ __launch_bounds__(256) void k_coef(const float* __restrict__ feat,
                                              const float* __restrict__ accS,
                                              const float* __restrict__ accS2,
                                              const float* __restrict__ c1w,
                                              const float* __restrict__ c1b,
                                              const float* __restrict__ c3w,
                                              const float* __restrict__ c3b,
                                              const float* __restrict__ gnw,
                                              const float* __restrict__ gnb,
                                              float* __restrict__ coeff) {
  const int gb  = threadIdx.x;   // 0..255 global group
  const int seg = gb >> 5;
  const int g   = gb & 31;
  const float invn = 1.0f / (float)NPTS;

  float S[8], S2[8], mean[8], var[8];
#pragma unroll
  for (int i = 0; i < 8; ++i) {
    S[i]  = accS [seg * CH + g * 8 + i];
    S2[i] = accS2[seg * CH + g * 8 + i];
    mean[i] = S[i] * invn;
    var[i]  = fmaxf(S2[i] * invn - mean[i] * mean[i], 0.0f);
  }
  float xf[8], xl[8];
  const size_t rowf = ((size_t)seg * NPTS) * CH + g * 8;
  const size_t rowl = ((size_t)seg * NPTS + (NPTS - 1)) * CH + g * 8;
#pragma unroll
  for (int i = 0; i < 8; ++i) { xf[i] = feat[rowf + i]; xl[i] = feat[rowl + i]; }

  // gate = sigmoid(conv1(mean)); a1 = gate * rsqrt(gate^2 var + eps) * gn_w
  float a1[8];
#pragma unroll
  for (int o = 0; o < 8; ++o) {
    float xg = c1b[o];
#pragma unroll
    for (int i = 0; i < 8; ++i) xg += c1w[o * 8 + i] * mean[i];
    float gate = 1.0f / (1.0f + expf(-xg));
    float inv  = rsqrtf(gate * gate * var[o] + EPS_GN);
    a1[o] = gate * inv * gnw[o];
  }

  // x2 channel means with zero-pad boundary correction
  float x2m[8];
#pragma unroll
  for (int o = 0; o < 8; ++o) {
    float t = 0.0f;
#pragma unroll
    for (int i = 0; i < 8; ++i) {
      const float w0 = c3w[o * 24 + i * 3 + 0];
      const float w1 = c3w[o * 24 + i * 3 + 1];
      const float w2 = c3w[o * 24 + i * 3 + 2];
      t += w0 * (S[i] - xl[i]) + w1 * S[i] + w2 * (S[i] - xf[i]);
    }
    x2m[o] = c3b[o] + t * invn;
  }

  // softmaxes: x11 = softmax(gn_b) (x1 means are exactly gn_b), x21 = softmax(x2m)
  float x11[8], x21[8];
  {
    float m1 = gnb[0], m2 = x2m[0];
#pragma unroll
    for (int o = 1; o < 8; ++o) { m1 = fmaxf(m1, gnb[o]); m2 = fmaxf(m2, x2m[o]); }
    float d1 = 0.0f, d2 = 0.0f;
#pragma unroll
    for (int o = 0; o < 8; ++o) {
      x11[o] = expf(gnb[o] - m1); d1 += x11[o];
      x21[o] = expf(x2m[o] - m2); d2 += x21[o];
    }
    d1 = 1.0f / d1; d2 = 1.0f / d2;
#pragma unroll
    for (int o = 0; o < 8; ++o) { x11[o] *= d1; x21[o] *= d2; }
  }

  // fold into linear-in-x coefficients: w[s] = K + P·x[s-1] + Q·x[s] + R·x[s+1]
  float P[8], Q[8], R[8];
#pragma unroll
  for (int i = 0; i < 8; ++i) {
    float p = 0.0f, qc = 0.0f, rr = 0.0f;
#pragma unroll
    for (int o = 0; o < 8; ++o) {
      const float s11 = x11[o];
      p  += s11 * c3w[o * 24 + i * 3 + 0];
      qc += s11 * c3w[o * 24 + i * 3 + 1];
      rr += s11 * c3w[o * 24 + i * 3 + 2];
    }
    P[i] = p; Q[i] = qc + x21[i] * a1[i]; R[i] = rr;
  }
  float K = 0.0f;
#pragma unroll
  for (int o = 0; o < 8; ++o)
    K += x11[o] * c3b[o] + x21[o] * (gnb[o] - a1[o] * mean[o]);

  float* cp = coeff + gb * 32;
  cp[0] = K;
#pragma unroll
  for (int i = 0; i < 8; ++i) { cp[4 + i] = P[i]; cp[12 + i] = Q[i]; cp[20 + i] = R[i]; }
}

// ---------------- kernel 3: main fused pass ----------------
__global__ __launch_bounds__(256) void k_main(const float* __restrict__ feat,
                                              const float* __restrict__ coeff,
                                              const float* __restrict__ fwp,
                                              float* __restrict__ out) {
  const int blk   = blockIdx.x;      // 2048 = NSEG * 256
  const int seg   = blk >> 8;
  const int chunk = blk & 255;       // 256 chunks of 128 rows
  const int g  = threadIdx.x & 31;   // group within segment
  const int dr = threadIdx.x >> 5;   // 0..7 (8 rows / iter)
  const int gb = seg * 32 + g;

  const float4* cp = (const float4*)(coeff + gb * 32);
  const float4 c0 = cp[0];
  const float4 P0 = cp[1], P1 = cp[2];
  const float4 Q0 = cp[3], Q1 = cp[4];
  const float4 R0 = cp[5], R1 = cp[6];
  const float K  = c0.x;
  const float fw = fwp[0];
  const float w1 = 1.0f - fw;

  const int r0 = chunk * 128;
  for (int r = r0 + dr; r < r0 + 128; r += 8) {
    const size_t row = (size_t)seg * NPTS + r;
    const float4* xp0 = (const float4*)(feat + row * CH + g * 8);
    const float4 a0 = xp0[0], a1 = xp0[1];
    float w = K
      + Q0.x * a0.x + Q0.y * a0.y + Q0.z * a0.z + Q0.w * a0.w
      + Q1.x * a1.x + Q1.y * a1.y + Q1.z * a1.z + Q1.w * a1.w;
    if (r > 0) {
      const float4* xm = xp0 - (CH / 4);
      const float4 m0 = xm[0], m1 = xm[1];
      w += P0.x * m0.x + P0.y * m0.y + P0.z * m0.z + P0.w * m0.w
         + P1.x * m1.x + P1.y * m1.y + P1.z * m1.z + P1.w * m1.w;
    }
    if (r < NPTS - 1) {
      const float4* xq = xp0 + (CH / 4);
      const float4 p0 = xq[0], p1 = xq[1];
      w += R0.x * p0.x + R0.y * p0.y + R0.z * p0.z + R0.w * p0.w
         + R1.x * p1.x + R1.y * p1.y + R1.z * p1.z + R1.w * p1.w;
    }
    const float sig   = 1.0f / (1.0f + __expf(-w));
    const float scale = w1 + fw * sig;
    float4 o0 = make_float4(a0.x * scale, a0.y * scale, a0.z * scale, a0.w * scale);
    float4 o1 = make_float4(a1.x * scale, a1.y * scale, a1.z * scale, a1.w * scale);
    float4* op = (float4*)(out + row * CH + g * 8);
    op[0] = o0; op[1] = o1;
  }
}

extern "C" void kernel_launch(void* const* d_in, const int* in_sizes, int n_in,
                              void* d_out, int out_size, void* d_ws, size_t ws_size,
                              hipStream_t stream) {
  const float* feat = (const float*)d_in[0];
  const float* c1w  = (const float*)d_in[1];
  const float* c1b  = (const float*)d_in[2];
  const float* c3w  = (const float*)d_in[3];
  const float* c3b  = (const float*)d_in[4];
  const float* gnw  = (const float*)d_in[5];
  const float* gnb  = (const float*)d_in[6];
  const float* fwp  = (const float*)d_in[7];
  // d_in[8] = offset (equal segments, compile-time constants used)
  float* out = (float*)d_out;
  float* ws  = (float*)d_ws;
  float* accS  = ws;
  float* accS2 = ws + NSEG * CH;
  float* coeff = ws + 2 * NSEG * CH;

  k_zero  <<<16,   256, 0, stream>>>(ws);
  k_reduce<<<1024, 256, 0, stream>>>(feat, accS, accS2);
  k_coef  <<<1,    256, 0, stream>>>(feat, accS, accS2, c1w, c1b, c3w, c3b, gnw, gnb, coeff);
  k_main  <<<2048, 256, 0, stream>>>(feat, coeff, fwp, out);
}

// Round 4
// 541.714 us; speedup vs baseline: 1.0474x; 1.0474x over previous
//
#include <hip/hip_runtime.h>
#include <math.h>

#define NSEG 8
#define NPTS 32768
#define CH   256
#define EPS_GN 1e-5f

// workspace layout (floats): part[2048*512] | coeff[256*32]
// part per reduce-block (stride 512): [0..255]=S per channel, [256..511]=S2
// coeff per group (stride 32): [0]=K, [4..11]=P, [12..19]=Q, [20..27]=R

__device__ __forceinline__ float dot8(float4 a0, float4 a1, float4 b0, float4 b1) {
  return a0.x * b0.x + a0.y * b0.y + a0.z * b0.z + a0.w * b0.w
       + a1.x * b1.x + a1.y * b1.y + a1.z * b1.z + a1.w * b1.w;
}

// ---------------- kernel 1: per-block partial Σx, Σx² (no atomics) ----------------
// 2048 blocks × 256 thr; block handles 128 consecutive rows (never crosses segment:
// 128 divides NPTS). 8 blocks/CU, 32 waves/CU for BW saturation.
__global__ __launch_bounds__(256) void k_reduce(const float* __restrict__ feat,
                                                float* __restrict__ part) {
  const int blk = blockIdx.x;        // 2048
  const int q  = threadIdx.x & 63;   // float4 column (channels 4q..4q+3)
  const int dr = threadIdx.x >> 6;   // 0..3
  const float4* f4 = (const float4*)feat;
  const size_t rowbase = (size_t)blk * 128;
  float4 s  = make_float4(0.f, 0.f, 0.f, 0.f);
  float4 s2 = make_float4(0.f, 0.f, 0.f, 0.f);
  for (int r = dr; r < 128; r += 4) {
    float4 v = f4[(rowbase + r) * (CH / 4) + q];
    s.x  += v.x;       s.y  += v.y;       s.z  += v.z;       s.w  += v.w;
    s2.x += v.x * v.x; s2.y += v.y * v.y; s2.z += v.z * v.z; s2.w += v.w * v.w;
  }
  __shared__ float4 rs[256];
  __shared__ float4 rq[256];
  rs[threadIdx.x] = s;
  rq[threadIdx.x] = s2;
  __syncthreads();
  if (threadIdx.x < 64) {
    float4 a = rs[q], b = rs[64 + q], c = rs[128 + q], d = rs[192 + q];
    float4 e = rq[q], f = rq[64 + q], g = rq[128 + q], h = rq[192 + q];
    float4 S  = make_float4(a.x + b.x + c.x + d.x, a.y + b.y + c.y + d.y,
                            a.z + b.z + c.z + d.z, a.w + b.w + c.w + d.w);
    float4 S2 = make_float4(e.x + f.x + g.x + h.x, e.y + f.y + g.y + h.y,
                            e.z + f.z + g.z + h.z, e.w + f.w + g.w + h.w);
    float4* pp = (float4*)(part + (size_t)blk * 512);
    pp[q]      = S;
    pp[64 + q] = S2;
  }
}

// ---------------- kernel 2: reduce partials + per-group coefficients ----------------
// 8 blocks (one per segment) × 256 threads.
__global__ __launch_bounds__(256) void k_coef(const float* __restrict__ feat,
                                              const float* __restrict__ part,
                                              const float* __restrict__ c1w,
                                              const float* __restrict__ c1b,
                                              const float* __restrict__ c3w,
                                              const float* __restrict__ c3b,
                                              const float* __restrict__ gnw,
                                              const float* __restrict__ gnb,
                                              float* __restrict__ coeff) {
  const int seg = blockIdx.x;
  const int c   = threadIdx.x;       // channel 0..255
  const float* pb = part + (size_t)seg * 256 * 512;   // 256 partial blocks / segment
  float S = 0.0f, S2 = 0.0f;
  for (int p = 0; p < 256; ++p) {
    S  += pb[(size_t)p * 512 + c];
    S2 += pb[(size_t)p * 512 + 256 + c];
  }
  __shared__ float sS[256], sS2[256], sxf[256], sxl[256];
  sS[c]  = S;
  sS2[c] = S2;
  sxf[c] = feat[(size_t)seg * NPTS * CH + c];
  sxl[c] = feat[((size_t)seg * NPTS + (NPTS - 1)) * CH + c];
  __syncthreads();

  if (c < 32) {
    const int g = c;
    const float invn = 1.0f / (float)NPTS;
    float Ss[8], Q2[8], mean[8], var[8], xf[8], xl[8];
#pragma unroll
    for (int i = 0; i < 8; ++i) {
      Ss[i] = sS [g * 8 + i];
      Q2[i] = sS2[g * 8 + i];
      mean[i] = Ss[i] * invn;
      var[i]  = fmaxf(Q2[i] * invn - mean[i] * mean[i], 0.0f);
      xf[i] = sxf[g * 8 + i];
      xl[i] = sxl[g * 8 + i];
    }
    // gate = sigmoid(conv1(mean)); a1 = gate * rsqrt(gate^2 var + eps) * gn_w
    float a1[8];
#pragma unroll
    for (int o = 0; o < 8; ++o) {
      float xg = c1b[o];
#pragma unroll
      for (int i = 0; i < 8; ++i) xg += c1w[o * 8 + i] * mean[i];
      float gate = 1.0f / (1.0f + expf(-xg));
      a1[o] = gate * rsqrtf(gate * gate * var[o] + EPS_GN) * gnw[o];
    }
    // x2 channel means with zero-pad boundary correction
    float x2m[8];
#pragma unroll
    for (int o = 0; o < 8; ++o) {
      float t = 0.0f;
#pragma unroll
      for (int i = 0; i < 8; ++i) {
        const float w0 = c3w[o * 24 + i * 3 + 0];
        const float w1 = c3w[o * 24 + i * 3 + 1];
        const float w2 = c3w[o * 24 + i * 3 + 2];
        t += w0 * (Ss[i] - xl[i]) + w1 * Ss[i] + w2 * (Ss[i] - xf[i]);
      }
      x2m[o] = c3b[o] + t * invn;
    }
    // x11 = softmax(gn_b) (x1 channel means are exactly gn_b), x21 = softmax(x2m)
    float x11[8], x21[8];
    {
      float m1 = gnb[0], m2 = x2m[0];
#pragma unroll
      for (int o = 1; o < 8; ++o) { m1 = fmaxf(m1, gnb[o]); m2 = fmaxf(m2, x2m[o]); }
      float d1 = 0.0f, d2 = 0.0f;
#pragma unroll
      for (int o = 0; o < 8; ++o) {
        x11[o] = expf(gnb[o] - m1); d1 += x11[o];
        x21[o] = expf(x2m[o] - m2); d2 += x21[o];
      }
      d1 = 1.0f / d1; d2 = 1.0f / d2;
#pragma unroll
      for (int o = 0; o < 8; ++o) { x11[o] *= d1; x21[o] *= d2; }
    }
    // fold into w[s] = K + P·x[s-1] + Q·x[s] + R·x[s+1]
    float P[8], Qc[8], R[8];
#pragma unroll
    for (int i = 0; i < 8; ++i) {
      float p = 0.0f, qq = 0.0f, rr = 0.0f;
#pragma unroll
      for (int o = 0; o < 8; ++o) {
        const float s11 = x11[o];
        p  += s11 * c3w[o * 24 + i * 3 + 0];
        qq += s11 * c3w[o * 24 + i * 3 + 1];
        rr += s11 * c3w[o * 24 + i * 3 + 2];
      }
      P[i] = p; Qc[i] = qq + x21[i] * a1[i]; R[i] = rr;
    }
    float K = 0.0f;
#pragma unroll
    for (int o = 0; o < 8; ++o)
      K += x11[o] * c3b[o] + x21[o] * (gnb[o] - a1[o] * mean[o]);

    float* cpw = coeff + (seg * 32 + g) * 32;
    cpw[0] = K;
#pragma unroll
    for (int i = 0; i < 8; ++i) { cpw[4 + i] = P[i]; cpw[12 + i] = Qc[i]; cpw[20 + i] = R[i]; }
  }
}

// ---------------- kernel 3: main fused pass, one read per row ----------------
// 2048 blocks × 256 thr; thread walks 16 consecutive rows of its group's 8 channels,
// carrying dP/dQ across iterations so each row is loaded exactly once.
__global__ __launch_bounds__(256) void k_main(const float* __restrict__ feat,
                                              const float* __restrict__ coeff,
                                              const float* __restrict__ fwp,
                                              float* __restrict__ out) {
  const int blk   = blockIdx.x;      // 2048
  const int seg   = blk >> 8;
  const int chunk = blk & 255;       // 128 rows per block
  const int g  = threadIdx.x & 31;   // group within segment
  const int tr = threadIdx.x >> 5;   // 0..7
  const int gb = seg * 32 + g;

  const float4* cp = (const float4*)(coeff + gb * 32);
  const float4 c0 = cp[0];
  const float4 P0 = cp[1], P1 = cp[2];
  const float4 Q0 = cp[3], Q1 = cp[4];
  const float4 R0 = cp[5], R1 = cp[6];
  const float K  = c0.x;
  const float fw = fwp[0];
  const float w1 = 1.0f - fw;

  const int base = chunk * 128 + tr * 16;       // row within segment
  const float4* f4 = (const float4*)feat;
  float4* o4 = (float4*)out;
  const size_t idx0 = ((size_t)seg * NPTS + base) * (CH / 4) + g * 2;

  float dPprev = 0.0f;
  if (base > 0) {
    float4 m0 = f4[idx0 - 64], m1 = f4[idx0 - 63];
    dPprev = dot8(P0, P1, m0, m1);
  }
  float4 xc0 = f4[idx0], xc1 = f4[idx0 + 1];
  float dQc = dot8(Q0, Q1, xc0, xc1);

#pragma unroll 4
  for (int s = 0; s < 16; ++s) {
    const size_t idx = idx0 + (size_t)s * 64;
    float4 xn0 = xc0, xn1 = xc1;
    float dRn = 0.0f;
    if (base + s + 1 < NPTS) {                  // false only for the last row
      xn0 = f4[idx + 64];
      xn1 = f4[idx + 65];
      dRn = dot8(R0, R1, xn0, xn1);
    }
    const float w = K + dPprev + dQc + dRn;
    const float scale = w1 + fw / (1.0f + __expf(-w));
    o4[idx]     = make_float4(xc0.x * scale, xc0.y * scale, xc0.z * scale, xc0.w * scale);
    o4[idx + 1] = make_float4(xc1.x * scale, xc1.y * scale, xc1.z * scale, xc1.w * scale);
    dPprev = dot8(P0, P1, xc0, xc1);
    dQc    = dot8(Q0, Q1, xn0, xn1);
    xc0 = xn0; xc1 = xn1;
  }
}

extern "C" void kernel_launch(void* const* d_in, const int* in_sizes, int n_in,
                              void* d_out, int out_size, void* d_ws, size_t ws_size,
                              hipStream_t stream) {
  const float* feat = (const float*)d_in[0];
  const float* c1w  = (const float*)d_in[1];
  const float* c1b  = (const float*)d_in[2];
  const float* c3w  = (const float*)d_in[3];
  const float* c3b  = (const float*)d_in[4];
  const float* gnw  = (const float*)d_in[5];
  const float* gnb  = (const float*)d_in[6];
  const float* fwp  = (const float*)d_in[7];
  // d_in[8] = offset (equal segments, compile-time constants)
  float* out = (float*)d_out;
  float* ws  = (float*)d_ws;
  float* part  = ws;                       // 2048*512 floats = 4 MB
  float* coeff = ws + 2048 * 512;          // 256*32 floats

  k_reduce<<<2048, 256, 0, stream>>>(feat, part);
  k_coef  <<<8,    256, 0, stream>>>(feat, part, c1w, c1b, c3w, c3b, gnw, gnb, coeff);
  k_main  <<<2048, 256, 0, stream>>>(feat, coeff, fwp, out);
}